// Round 4
// baseline (1635.379 us; speedup 1.0000x reference)
//
#include <hip/hip_runtime.h>
#include <hip/hip_bf16.h>
#include <math.h>
#include <stdint.h>

#define S_TOK 8192
#define D_DIM 1024
#define F_DIM 4096
#define E_EXP 8
#define C_CAP 2560   // int(1.25 * 8192 * 2 / 8)

typedef __bf16 bf16x8_t __attribute__((ext_vector_type(8)));
typedef __bf16 bf16x4_t __attribute__((ext_vector_type(4)));
typedef float f32x4_t __attribute__((ext_vector_type(4)));

// async global->LDS, 16B per lane; LDS dest = wave-uniform base + lane*16
__device__ __forceinline__ void async_copy16(const void* g, void* l) {
  __builtin_amdgcn_global_load_lds(
      (const __attribute__((address_space(1))) unsigned int*)g,
      (__attribute__((address_space(3))) unsigned int*)l, 16, 0, 0);
}

// ---------------- routing: logits -> softmax -> top2; also emits x_bf16 ----------------
__global__ __launch_bounds__(256) void routing_kernel(
    const float* __restrict__ x, const float* __restrict__ wg,
    __bf16* __restrict__ x_bf, int* __restrict__ asg_e, float* __restrict__ asg_g,
    float* __restrict__ imp_sum)
{
  __shared__ float s_imp[E_EXP];
  const int tid = threadIdx.x, lane = tid & 63, w = tid >> 6;
  if (tid < E_EXP) s_imp[tid] = 0.f;
  __syncthreads();
  const int t = blockIdx.x * 4 + w;   // one wave per token

  const float4* xp = (const float4*)(x + (size_t)t * D_DIM);
  float4 xv[4];
#pragma unroll
  for (int j = 0; j < 4; j++) xv[j] = xp[lane + 64 * j];

  // free bf16 conversion of x (needed by GEMM1)
#pragma unroll
  for (int j = 0; j < 4; j++) {
    bf16x4_t o;
    o[0] = (__bf16)xv[j].x; o[1] = (__bf16)xv[j].y;
    o[2] = (__bf16)xv[j].z; o[3] = (__bf16)xv[j].w;
    *(bf16x4_t*)(x_bf + (size_t)t * D_DIM + (size_t)(lane + 64 * j) * 4) = o;
  }

  float acc[E_EXP];
#pragma unroll
  for (int e = 0; e < E_EXP; e++) acc[e] = 0.f;
#pragma unroll
  for (int e = 0; e < E_EXP; e++) {
    const float4* wp = (const float4*)(wg + (size_t)e * D_DIM);
#pragma unroll
    for (int j = 0; j < 4; j++) {
      const float4 wv = wp[lane + 64 * j];
      acc[e] += xv[j].x * wv.x + xv[j].y * wv.y + xv[j].z * wv.z + xv[j].w * wv.w;
    }
  }
#pragma unroll
  for (int e = 0; e < E_EXP; e++)
    for (int off = 32; off > 0; off >>= 1) acc[e] += __shfl_xor(acc[e], off);

  if (lane == 0) {
    float m = acc[0];
#pragma unroll
    for (int e = 1; e < E_EXP; e++) m = fmaxf(m, acc[e]);
    float p[E_EXP], s = 0.f;
#pragma unroll
    for (int e = 0; e < E_EXP; e++) { p[e] = expf(acc[e] - m); s += p[e]; }
    const float inv = 1.f / s;
#pragma unroll
    for (int e = 0; e < E_EXP; e++) p[e] *= inv;
    // top-2, first-index wins ties (matches lax.top_k)
    int e0 = 0; float v0 = p[0];
#pragma unroll
    for (int e = 1; e < E_EXP; e++) if (p[e] > v0) { v0 = p[e]; e0 = e; }
    int e1 = -1; float v1 = -1.f;
#pragma unroll
    for (int e = 0; e < E_EXP; e++) if (e != e0 && p[e] > v1) { v1 = p[e]; e1 = e; }
    asg_e[2 * t] = e0; asg_g[2 * t] = v0;
    asg_e[2 * t + 1] = e1; asg_g[2 * t + 1] = v1;
#pragma unroll
    for (int e = 0; e < E_EXP; e++) atomicAdd(&s_imp[e], p[e]);
  }
  __syncthreads();
  if (tid < E_EXP) atomicAdd(&imp_sum[tid], s_imp[tid]);
}

// ---------------- fp32 -> bf16 weight conversion (W1 + W2 fused in one launch) --------
__global__ __launch_bounds__(256) void cvt2_kernel(
    const float* __restrict__ s1, const float* __restrict__ s2,
    __bf16* __restrict__ d1, __bf16* __restrict__ d2, int n4each)
{
  const int stride = gridDim.x * blockDim.x;
  for (int i = blockIdx.x * blockDim.x + threadIdx.x; i < 2 * n4each; i += stride) {
    const int half = (i >= n4each);
    const int j = half ? (i - n4each) : i;
    const float4 v = half ? ((const float4*)s2)[j] : ((const float4*)s1)[j];
    bf16x4_t o;
    o[0] = (__bf16)v.x; o[1] = (__bf16)v.y; o[2] = (__bf16)v.z; o[3] = (__bf16)v.w;
    if (half) ((bf16x4_t*)d2)[j] = o; else ((bf16x4_t*)d1)[j] = o;
  }
}

// ---------------- positions: ordered per-expert scan + slot tables + aux ----------------
// (slot_token pre-initialized to -1 via hipMemsetAsync in the launcher)
// All expert-indexed per-thread arrays use unrolled compare-select (rule #20).
__global__ __launch_bounds__(256) void positions_kernel(
    const int* __restrict__ asg_e, const float* __restrict__ asg_g,
    const float* __restrict__ imp_sum, int* __restrict__ slot_token,
    float* __restrict__ slot_gate, int* __restrict__ cnt_g, float* __restrict__ aux_out)
{
  __shared__ int lcnt[E_EXP * 256];
  __shared__ int tot[E_EXP];
  const int tid = threadIdx.x;
  int cnt[E_EXP];
#pragma unroll
  for (int e = 0; e < E_EXP; e++) cnt[e] = 0;
  const int a0 = tid * 64;   // 16384 assignments / 256 threads
  for (int j = 0; j < 64; j++) {
    const int ae = asg_e[a0 + j];
#pragma unroll
    for (int e = 0; e < E_EXP; e++) cnt[e] += (ae == e) ? 1 : 0;
  }
#pragma unroll
  for (int e = 0; e < E_EXP; e++) lcnt[e * 256 + tid] = cnt[e];
  __syncthreads();
  if (tid < E_EXP) {   // exclusive prefix per expert (serial 256: cheap)
    int run = 0;
    for (int i = 0; i < 256; i++) { const int v = lcnt[tid * 256 + i]; lcnt[tid * 256 + i] = run; run += v; }
    tot[tid] = run;
    cnt_g[tid] = run;
  }
  __syncthreads();
  int base[E_EXP];
#pragma unroll
  for (int e = 0; e < E_EXP; e++) base[e] = lcnt[e * 256 + tid];
  for (int j = 0; j < 64; j++) {
    const int a = a0 + j;
    const int ae = asg_e[a];
    int pp = 0;
#pragma unroll
    for (int e = 0; e < E_EXP; e++) {
      if (ae == e) { pp = base[e]; base[e] = pp + 1; }
    }
    if (pp < C_CAP) { slot_token[ae * C_CAP + pp] = a >> 1; slot_gate[ae * C_CAP + pp] = asg_g[a]; }
  }
  if (tid == 0) {
    float aux = 0.f;
#pragma unroll
    for (int e = 0; e < E_EXP; e++) aux += imp_sum[e] * (float)tot[e];
    aux_out[0] = (float)E_EXP * aux / ((float)S_TOK * (float)S_TOK);
  }
}

// ---------------- grouped GEMM: BMx256xBK64, 512 thr (8 waves 2Mx4N), dbuf 2-phase ----
// m230-V0 geometry (measured 682 TF dense / ~660 grouped): 256^2 tile, 8 waves, wave
// tile (BM/2)x64, simple 2-phase dbuf loop (best util/occ structure from round 2):
//   STAGE(buf^1, t+1) issued FIRST -> COMPUTE(buf) [24 ds_read_b128 + 64 MFMA/wave]
//   -> vmcnt(0) -> s_barrier   (one wait+barrier per K-tile)
// vs round 2 (128^2, 4 waves): 2x the MFMA per barrier interval per wave, half the
// staged bytes per FLOP, same resident-wave count (8/CU).
// MODE 0: BM=256 (LDS 128 KiB; ran fine at 512 thr in round 1).  MODE 1: BM=128
// (96 KiB; 640 blocks -> better tail packing than 320, acc only 64 regs).
// LDS: row-major [rows][128 B]; within a row, 16B chunk p holds logical chunk
// (p ^ (row&7)).  Swizzle applied on the GLOBAL source address (global_load_lds dest
// pinned to base+lane*16); reads de-swizzle.  0 conflicts measured rounds 0-2.
// MODE 0: H = gelu(gather(x_bf) @ W1[e]^T + b1)        (K=D, N=F)
// MODE 1: y[tok] += g * (H @ W2[e]^T + b2 + x[tok])    (K=F, N=D, atomic combine)
#define WAIT_VM0 asm volatile("s_waitcnt vmcnt(0)" ::: "memory")

template <int MODE>
__global__ __launch_bounds__(512, 2) void moe_gemm(
    const __bf16* __restrict__ A, const __bf16* __restrict__ Bw,
    const float* __restrict__ bias, const int* __restrict__ slot_token,
    const float* __restrict__ slot_gate, const float* __restrict__ xres,
    const int* __restrict__ cnt, __bf16* __restrict__ Hout, float* __restrict__ y,
    int MT, int NT, int N, int K)
{
  constexpr int BM = (MODE == 0) ? 256 : 128;   // BN = 256 always
  constexpr int MFRAG = BM / 32;                // m-fragments per wave: 8 or 4
  constexpr int MQ = MFRAG / 4;                 // m-quarters (af reload groups): 2 or 1
  constexpr int AGROUPS = BM / 64;              // A staging row-groups per wave: 4 or 2

  // per-XCD contiguous tiles + 2-row m-group swizzle for L2 locality
  const int ntiles = gridDim.x;
  const int xcd = blockIdx.x & 7, slot = blockIdx.x >> 3;
  const int tile = xcd * (ntiles >> 3) + slot;
  const int e = tile / (MT * NT);
  const int t_ = tile % (MT * NT);
  const int grp = t_ / (2 * NT), rem = t_ % (2 * NT);
  const int mt = grp * 2 + (rem & 1), nt = rem >> 1;
  const int m0 = mt * BM, n0 = nt * 256;
  if (m0 >= cnt[e]) return;   // whole tile beyond this expert's occupancy

  const int tid = threadIdx.x, lane = tid & 63, w = tid >> 6;   // w in 0..7
  const int wm = w >> 2, wn = w & 3;                             // 2M x 4N waves

  __shared__ __align__(16) unsigned short sA[2][BM][64];    // 64 or 32 KB
  __shared__ __align__(16) unsigned short sB[2][256][64];   // 64 KB

  const int rstage = lane >> 3;            // row within 8-row stage group (== row&7)
  const int cstage = (lane & 7) ^ rstage;  // XOR-swizzled 16B chunk to fetch
  const int wArow = w * (BM / 8);          // wave stages A rows [wArow, wArow+BM/8)
  const int wBrow = w * 32;                // and B rows [wBrow, wBrow+32)

  const char* gA[AGROUPS];
  const char* gB[4];
#pragma unroll
  for (int i = 0; i < AGROUPS; i++) {
    const int rowA = wArow + i * 8 + rstage;
    size_t arow;
    if (MODE == 0) {
      int tok = slot_token[e * C_CAP + m0 + rowA];
      if (tok < 0) tok = 0;   // empty slot: junk row 0, epilogue-discarded downstream
      arow = (size_t)tok * (size_t)K;
    } else {
      arow = ((size_t)(e * C_CAP + m0 + rowA)) * (size_t)K;
    }
    gA[i] = (const char*)(A + arow) + cstage * 16;
  }
#pragma unroll
  for (int i = 0; i < 4; i++) {
    const int rowB = wBrow + i * 8 + rstage;
    gB[i] = (const char*)(Bw + ((size_t)(e * N + n0 + rowB)) * (size_t)K) + cstage * 16;
  }

#define STAGE(BUF, kt) do {                                                         \
    const size_t koff_ = (size_t)(kt) * 128;                                        \
    _Pragma("unroll")                                                               \
    for (int i_ = 0; i_ < AGROUPS; i_++)                                            \
      async_copy16(gA[i_] + koff_, (void*)&sA[BUF][wArow + i_ * 8][0]);             \
    _Pragma("unroll")                                                               \
    for (int i_ = 0; i_ < 4; i_++)                                                  \
      async_copy16(gB[i_] + koff_, (void*)&sB[BUF][wBrow + i_ * 8][0]);             \
  } while (0)

  f32x4_t acc[MFRAG][4];
#pragma unroll
  for (int mi = 0; mi < MFRAG; mi++)
#pragma unroll
    for (int ni = 0; ni < 4; ni++) acc[mi][ni] = (f32x4_t){0.f, 0.f, 0.f, 0.f};

  const int fr = lane & 15;          // fragment row within 16
  const int fq = lane >> 4;          // quadrant -> k chunk

// de-swizzled LDS reads: row*64 + ((chunk ^ (row&7))*8) halfs.
// bfv loaded once per kk, af reloaded per m-quarter (keeps live frags at 8x bf16x8).
#define COMPUTE(BUF)                                                                \
  _Pragma("unroll")                                                                 \
  for (int kk = 0; kk < 2; kk++) {                                                  \
    bf16x8_t bfv[4];                                                                \
    _Pragma("unroll")                                                               \
    for (int ni = 0; ni < 4; ni++) {                                                \
      const int row = wn * 64 + ni * 16 + fr;                                       \
      const int chk = (kk * 4 + fq) ^ (row & 7);                                    \
      bfv[ni] = *(const bf16x8_t*)&sB[BUF][row][chk * 8];                           \
    }                                                                               \
    _Pragma("unroll")                                                               \
    for (int mh = 0; mh < MQ; mh++) {                                               \
      bf16x8_t af[4];                                                               \
      _Pragma("unroll")                                                             \
      for (int mi = 0; mi < 4; mi++) {                                              \
        const int row = wm * (BM / 2) + (mh * 4 + mi) * 16 + fr;                    \
        const int chk = (kk * 4 + fq) ^ (row & 7);                                  \
        af[mi] = *(const bf16x8_t*)&sA[BUF][row][chk * 8];                          \
      }                                                                             \
      __builtin_amdgcn_s_setprio(1);                                                \
      _Pragma("unroll")                                                             \
      for (int mi = 0; mi < 4; mi++)                                                \
        _Pragma("unroll")                                                           \
        for (int ni = 0; ni < 4; ni++)                                              \
          acc[mh * 4 + mi][ni] = __builtin_amdgcn_mfma_f32_16x16x32_bf16(           \
              af[mi], bfv[ni], acc[mh * 4 + mi][ni], 0, 0, 0);                      \
      __builtin_amdgcn_s_setprio(0);                                                \
    }                                                                               \
  }

  const int NTILES = K >> 6;   // 16 (mode 0) or 64 (mode 1): always even
  // prologue: tile 0 staged and visible
  STAGE(0, 0);
  WAIT_VM0;
  __builtin_amdgcn_s_barrier();

  for (int t = 0; t < NTILES; t += 2) {
    // tile t (buf 0): prefetch t+1 into buf 1, compute buf 0
    STAGE(1, t + 1);              // t+1 < NTILES always (NTILES even)
    COMPUTE(0);
    WAIT_VM0;                     // tile t+1 resident
    __builtin_amdgcn_s_barrier();
    // tile t+1 (buf 1): prefetch t+2 into buf 0, compute buf 1
    if (t + 2 < NTILES) {
      STAGE(0, t + 2);
      COMPUTE(1);
      WAIT_VM0;
      __builtin_amdgcn_s_barrier();
    } else {
      COMPUTE(1);                 // last tile: no prefetch, no barrier needed
    }
  }

  // C/D layout: col = lane&15, row = (lane>>4)*4 + reg  (m89-verified)
  const int col_lo = lane & 15;
  const int row_hi = (lane >> 4) * 4;
  if (MODE == 0) {
#pragma unroll
    for (int ni = 0; ni < 4; ni++) {
      const int gcol = n0 + wn * 64 + ni * 16 + col_lo;
      const float bv = bias[e * N + gcol];
#pragma unroll
      for (int mi = 0; mi < MFRAG; mi++) {
#pragma unroll
        for (int r = 0; r < 4; r++) {
          const int grow = m0 + wm * (BM / 2) + mi * 16 + row_hi + r;
          const float v = acc[mi][ni][r] + bv;
          const float gl = 0.5f * v * (1.0f + erff(v * 0.70710678118654752f));  // exact gelu
          Hout[((size_t)(e * C_CAP + grow)) * (size_t)N + gcol] = (__bf16)gl;
        }
      }
    }
  } else {
#pragma unroll
    for (int mi = 0; mi < MFRAG; mi++) {
#pragma unroll
      for (int r = 0; r < 4; r++) {
        const int slotI = e * C_CAP + m0 + wm * (BM / 2) + mi * 16 + row_hi + r;
        const int tok = slot_token[slotI];
        if (tok < 0) continue;
        const float g = slot_gate[slotI];
        const size_t trow = (size_t)tok * (size_t)N;
#pragma unroll
        for (int ni = 0; ni < 4; ni++) {
          const int gcol = n0 + wn * 64 + ni * 16 + col_lo;
          const float v = acc[mi][ni][r] + bias[e * N + gcol] + xres[trow + gcol];
          atomicAdd(&y[trow + gcol], g * v);   // <=2 adds per element
        }
      }
    }
  }
#undef STAGE
#undef COMPUTE
}

extern "C" void kernel_launch(void* const* d_in, const int* in_sizes, int n_in,
                              void* d_out, int out_size, void* d_ws, size_t ws_size,
                              hipStream_t stream) {
  const float* x  = (const float*)d_in[0];
  const float* wg = (const float*)d_in[1];
  const float* W1 = (const float*)d_in[2];
  const float* b1 = (const float*)d_in[3];
  const float* W2 = (const float*)d_in[4];
  const float* b2 = (const float*)d_in[5];
  float* y = (float*)d_out;

  // workspace layout (~320 MB)
  char* p = (char*)d_ws;
  __bf16* x_bf = (__bf16*)p;    p += (size_t)S_TOK * D_DIM * 2;
  __bf16* w1_bf = (__bf16*)p;   p += (size_t)E_EXP * F_DIM * D_DIM * 2;
  __bf16* w2_bf = (__bf16*)p;   p += (size_t)E_EXP * F_DIM * D_DIM * 2;
  __bf16* Hbuf = (__bf16*)p;    p += (size_t)E_EXP * C_CAP * F_DIM * 2;
  int* slot_token = (int*)p;    p += (size_t)E_EXP * C_CAP * 4;
  float* slot_gate = (float*)p; p += (size_t)E_EXP * C_CAP * 4;
  int* asg_e = (int*)p;         p += (size_t)S_TOK * 2 * 4;
  float* asg_g = (float*)p;     p += (size_t)S_TOK * 2 * 4;
  float* imp_sum = (float*)p;   p += 64;
  int* cnt_g = (int*)p;         p += 64;

  hipMemsetAsync(d_out, 0, ((size_t)S_TOK * D_DIM + 1) * sizeof(float), stream);
  hipMemsetAsync(imp_sum, 0, E_EXP * sizeof(float), stream);
  hipMemsetAsync(slot_token, 0xFF, (size_t)E_EXP * C_CAP * sizeof(int), stream);  // -1

  routing_kernel<<<S_TOK / 4, 256, 0, stream>>>(x, wg, x_bf, asg_e, asg_g, imp_sum);
  cvt2_kernel<<<4096, 256, 0, stream>>>(W1, W2, w1_bf, w2_bf, E_EXP * F_DIM * D_DIM / 4);
  positions_kernel<<<1, 256, 0, stream>>>(asg_e, asg_g, imp_sum, slot_token, slot_gate,
                                          cnt_g, y + (size_t)S_TOK * D_DIM);
  // GEMM1: 256x256 tiles -> 8 * 10 * 16 = 1280 blocks of 512 threads (5 clean rounds)
  moe_gemm<0><<<E_EXP * 10 * 16, 512, 0, stream>>>(x_bf, w1_bf, b1, slot_token, nullptr,
                                                   nullptr, cnt_g, Hbuf, nullptr,
                                                   10, 16, F_DIM, D_DIM);
  // GEMM2: 128x256 tiles -> 8 * 20 * 4 = 640 blocks of 512 threads
  moe_gemm<1><<<E_EXP * 20 * 4, 512, 0, stream>>>(Hbuf, w2_bf, b2, slot_token, slot_gate,
                                                  x, cnt_g, nullptr, y,
                                                  20, 4, D_DIM, F_DIM);
}